// Round 1
// baseline (10302.212 us; speedup 1.0000x reference)
//
#include <hip/hip_runtime.h>
#include <hip/hip_fp16.h>

// ============================================================================
// GRU scan, T=256, cells=B*A=512, H=512.
//   x_gates = ins @ Wi + bi  (fused, per step)
//   hg      = h   @ Wh
//   r=sig(xr+hr), z=sig(xz+hz), n=tanh(xn + r*(hn+bhn))
//   new_h=(1-z)n+z*h ; carry = reset ? 0 : new_h ; ys[t]=new_h
//
// Decomposition: 16 independent "mg" pipelines of 32 cells each. Each pipeline
// = 16 workgroups (ng = 32-column slice of H), per-step sync via a 16-wg
// atomic generation barrier (no grid-wide barrier). blockIdx swizzled so one
// pipeline lives on one XCD (round-robin dispatch assumption; perf-only).
//
// Per wg: 4 waves = 4 k-quarters (K=128 each). Weights (6 streams: Wi/Wh x
// r/z/n, f16) live in 192 VGPRs/lane for the whole kernel. A-fragments load
// direct global->VGPR in MFMA A-layout. LDS only for 4-way k-reduction.
// mfma_f32_32x32x16_f16: A lane l: m=l&31, k=8*(l>>5)+j ; B: n=l&31, same k ;
// C: col=l&31, row=(reg&3)+8*(reg>>2)+4*(l>>5).
// ============================================================================

#define T_STEPS 256
#define NCELL   512
#define HD      512
#define G3      1536

typedef _Float16 f16;
typedef _Float16 half8   __attribute__((ext_vector_type(8)));
typedef float    floatx16 __attribute__((ext_vector_type(16)));
typedef float    float4v  __attribute__((ext_vector_type(4)));

// ws layout (bytes):
//   [0, 3145728)            weight packs f16: [ng(16)][s(6)][it(32)][lane(64)][j(8)]
//   [3145728, 4194304)      h ping-pong: 2 x 512x512 f16
//   [4194304, 4198400)      barrier counters (16, stride 128B)
#define PACKS_ELEMS (16 * 6 * 32 * 64 * 8)
#define HBUF_OFF    (PACKS_ELEMS * 2)
#define HBUF_ELEMS  (NCELL * HD)
#define CNT_OFF     (HBUF_OFF + 2 * HBUF_ELEMS * 2)

__global__ void pack_weights(const float* __restrict__ Wi,
                             const float* __restrict__ Wh,
                             f16* __restrict__ packs) {
    int idx = blockIdx.x * blockDim.x + threadIdx.x;
    if (idx >= PACKS_ELEMS) return;
    int j  = idx & 7;
    int l  = (idx >> 3) & 63;
    int it = (idx >> 9) & 31;
    int s  = (idx >> 14) % 6;
    int ng = idx / (6 << 14);
    int k    = it * 16 + (l >> 5) * 8 + j;                 // MFMA B k-index
    int gcol = (s % 3) * 512 + ng * 32 + (l & 31);         // gate column
    const float* W = (s < 3) ? Wi : Wh;
    packs[idx] = (f16)W[(size_t)k * G3 + gcol];
}

__launch_bounds__(256, 1)
__global__ void gru_scan(const float* __restrict__ ins,
                         const int*   __restrict__ resets,
                         const float* __restrict__ bi,
                         const float* __restrict__ bhn,
                         const f16*   __restrict__ packs,
                         f16*         __restrict__ hbuf,
                         int*         __restrict__ cnt,
                         float*       __restrict__ out) {
    __shared__ float red[3][4][4][64][4];   // 48 KB: [wave-1][acc][quad][lane][4]

    const int bid  = blockIdx.x;
    const int xcd  = bid & 7;
    const int rest = bid >> 3;
    const int ng   = rest & 15;             // 32-column slice of H
    const int mg   = xcd + 8 * (rest >> 4); // 32-cell pipeline id (XCD-local)
    const int tid  = threadIdx.x;
    const int lane = tid & 63;
    const int w    = tid >> 6;              // wave = k-quarter
    const int lm   = lane & 31;
    const int lh   = lane >> 5;

    // ---- persistent B fragments: 6 streams x 8 k-iters, 192 VGPRs/lane ----
    half8 bw[6][8];
    {
        const half8* p = (const half8*)packs;
#pragma unroll
        for (int s = 0; s < 6; ++s)
#pragma unroll
            for (int itl = 0; itl < 8; ++itl)
                bw[s][itl] = p[((ng * 6 + s) * 32 + (w * 8 + itl)) * 64 + lane];
    }

    // biases for wave-0 elementwise (static, keep in regs)
    const int col0 = ng * 32 + lm;
    const float bir = bi[col0], biz = bi[512 + col0], bin = bi[1024 + col0];
    const float bhv = bhn[col0];

    const int cell_a = mg * 32 + lm;          // A-fragment row (cell)
    const int kbase  = w * 128 + lh * 8;      // A-fragment k base for this lane
    const f16* hb0 = hbuf;
    const f16* hb1 = hbuf + HBUF_ELEMS;

    // ---- prefetch x(t=0) fp32, convert to f16 fragments ----
    float4v xa[8], xb[8];
    {
        const float* xr0 = ins + (size_t)cell_a * HD + kbase;
#pragma unroll
        for (int itl = 0; itl < 8; ++itl) {
            const float4v* px = (const float4v*)(xr0 + itl * 16);
            xa[itl] = px[0];
            xb[itl] = px[1];
        }
    }
    half8 xf[8];
#pragma unroll
    for (int itl = 0; itl < 8; ++itl) {
        half8 v;
#pragma unroll
        for (int e = 0; e < 4; ++e) { v[e] = (f16)xa[itl][e]; v[4 + e] = (f16)xb[itl][e]; }
        xf[itl] = v;
    }

    for (int t = 0; t < T_STEPS; ++t) {
        const f16* hr_ = (t & 1) ? hb1 : hb0;
        f16*       hw_ = (f16*)((t & 1) ? hb0 : hb1);

        // h fragments for this step (critical path: issue first)
        half8 hf[8];
#pragma unroll
        for (int itl = 0; itl < 8; ++itl)
            hf[itl] = *(const half8*)(hr_ + (size_t)cell_a * HD + kbase + itl * 16);

        // prefetch x(t+1) fp32 (independent of h; hides HBM latency)
        {
            int tn = (t + 1 < T_STEPS) ? (t + 1) : t;
            const float* xrn = ins + ((size_t)tn * NCELL + cell_a) * HD + kbase;
#pragma unroll
            for (int itl = 0; itl < 8; ++itl) {
                const float4v* px = (const float4v*)(xrn + itl * 16);
                xa[itl] = px[0];
                xb[itl] = px[1];
            }
        }

        // ---- MFMA: 6 streams x 8 iters over this wave's k-quarter ----
        floatx16 ar, az, anx, anh;
#pragma unroll
        for (int i = 0; i < 16; ++i) { ar[i] = 0.f; az[i] = 0.f; anx[i] = 0.f; anh[i] = 0.f; }
#pragma unroll
        for (int itl = 0; itl < 8; ++itl) {
            ar  = __builtin_amdgcn_mfma_f32_32x32x16_f16(xf[itl], bw[0][itl], ar,  0, 0, 0);
            az  = __builtin_amdgcn_mfma_f32_32x32x16_f16(xf[itl], bw[1][itl], az,  0, 0, 0);
            anx = __builtin_amdgcn_mfma_f32_32x32x16_f16(xf[itl], bw[2][itl], anx, 0, 0, 0);
            ar  = __builtin_amdgcn_mfma_f32_32x32x16_f16(hf[itl], bw[3][itl], ar,  0, 0, 0);
            az  = __builtin_amdgcn_mfma_f32_32x32x16_f16(hf[itl], bw[4][itl], az,  0, 0, 0);
            anh = __builtin_amdgcn_mfma_f32_32x32x16_f16(hf[itl], bw[5][itl], anh, 0, 0, 0);
        }

        // convert x(t+1) to f16 frags (after last use of xf this step)
#pragma unroll
        for (int itl = 0; itl < 8; ++itl) {
            half8 v;
#pragma unroll
            for (int e = 0; e < 4; ++e) { v[e] = (f16)xa[itl][e]; v[4 + e] = (f16)xb[itl][e]; }
            xf[itl] = v;
        }

        // ---- k-reduction: waves 1..3 dump partials, wave 0 sums ----
        if (w != 0) {
#pragma unroll
            for (int q = 0; q < 4; ++q) {
                float4v v;
                v[0] = ar[4*q]; v[1] = ar[4*q+1]; v[2] = ar[4*q+2]; v[3] = ar[4*q+3];
                *(float4v*)&red[w - 1][0][q][lane][0] = v;
                v[0] = az[4*q]; v[1] = az[4*q+1]; v[2] = az[4*q+2]; v[3] = az[4*q+3];
                *(float4v*)&red[w - 1][1][q][lane][0] = v;
                v[0] = anx[4*q]; v[1] = anx[4*q+1]; v[2] = anx[4*q+2]; v[3] = anx[4*q+3];
                *(float4v*)&red[w - 1][2][q][lane][0] = v;
                v[0] = anh[4*q]; v[1] = anh[4*q+1]; v[2] = anh[4*q+2]; v[3] = anh[4*q+3];
                *(float4v*)&red[w - 1][3][q][lane][0] = v;
            }
        }
        __syncthreads();

        if (w == 0) {
#pragma unroll
            for (int ww = 0; ww < 3; ++ww) {
#pragma unroll
                for (int q = 0; q < 4; ++q) {
                    float4v v0 = *(const float4v*)&red[ww][0][q][lane][0];
                    float4v v1 = *(const float4v*)&red[ww][1][q][lane][0];
                    float4v v2 = *(const float4v*)&red[ww][2][q][lane][0];
                    float4v v3 = *(const float4v*)&red[ww][3][q][lane][0];
#pragma unroll
                    for (int e = 0; e < 4; ++e) {
                        ar[4*q+e]  += v0[e];
                        az[4*q+e]  += v1[e];
                        anx[4*q+e] += v2[e];
                        anh[4*q+e] += v3[e];
                    }
                }
            }
            // ---- elementwise GRU update for [32 cells x 32 cols] ----
#pragma unroll
            for (int e = 0; e < 16; ++e) {
                int row  = (e & 3) + 8 * (e >> 2) + 4 * lh;
                int cell = mg * 32 + row;
                float var = ar[e]  + bir;
                float vaz = az[e]  + biz;
                float vnx = anx[e] + bin;
                float vnh = anh[e] + bhv;
                float r = 1.0f / (1.0f + __expf(-var));
                float z = 1.0f / (1.0f + __expf(-vaz));
                float hp = (float)hr_[(size_t)cell * HD + col0];
                float narg = vnx + r * vnh;
                narg = fminf(fmaxf(narg, -30.f), 30.f);  // avoid inf/inf in tanh
                float ex = __expf(2.f * narg);
                float n  = (ex - 1.f) / (ex + 1.f);
                float nh = (1.f - z) * n + z * hp;
                out[((size_t)t * NCELL + cell) * HD + col0] = nh;   // pre-reset output
                int rs = resets[t * NCELL + cell];
                hw_[(size_t)cell * HD + col0] = rs ? (f16)0.f : (f16)nh;
            }
        }

        // ---- 16-wg pipeline barrier (generation count, XCD-local line) ----
        __threadfence();              // release h-writes (wave 0's stores)
        __syncthreads();
        if (tid == 0) {
            atomicAdd(&cnt[mg * 32], 1);
            int target = 16 * (t + 1);
            while (__hip_atomic_load(&cnt[mg * 32], __ATOMIC_RELAXED,
                                     __HIP_MEMORY_SCOPE_AGENT) < target) { }
        }
        __syncthreads();
        __threadfence();              // acquire: invalidate L1 before next h reads
    }
}

extern "C" void kernel_launch(void* const* d_in, const int* in_sizes, int n_in,
                              void* d_out, int out_size, void* d_ws, size_t ws_size,
                              hipStream_t stream) {
    const float* ins    = (const float*)d_in[0];
    const int*   resets = (const int*)  d_in[1];
    const float* Wi     = (const float*)d_in[2];
    const float* bi     = (const float*)d_in[3];
    const float* Wh     = (const float*)d_in[4];
    const float* bhn    = (const float*)d_in[5];
    float* out = (float*)d_out;

    char* ws = (char*)d_ws;
    f16* packs = (f16*)ws;
    f16* hbuf  = (f16*)(ws + HBUF_OFF);
    int* cnt   = (int*)(ws + CNT_OFF);

    // zero h ping-pong buffers + barrier counters (re-poisoned to 0xAA each call)
    hipMemsetAsync(ws + HBUF_OFF, 0, (size_t)2 * HBUF_ELEMS * 2 + 4096, stream);

    pack_weights<<<(PACKS_ELEMS + 255) / 256, 256, 0, stream>>>(Wi, Wh, packs);
    gru_scan<<<256, 256, 0, stream>>>(ins, resets, bi, bhn, packs, hbuf, cnt, out);
}